// Round 8
// baseline (5831.262 us; speedup 1.0000x reference)
//
#include <hip/hip_runtime.h>
#include <hip/hip_bf16.h>

typedef _Float16 half8 __attribute__((ext_vector_type(8)));
typedef _Float16 half4 __attribute__((ext_vector_type(4)));
typedef float floatx4 __attribute__((ext_vector_type(4)));

__device__ __forceinline__ float bfu2f(unsigned short u) {
  return __uint_as_float(((unsigned)u) << 16);
}

__device__ __forceinline__ void gld16(const void* g, void* l) {
  __builtin_amdgcn_global_load_lds((const __attribute__((address_space(1))) void*)g,
                                   (__attribute__((address_space(3))) void*)l, 16, 0, 0);
}

// wait own vmcnt(0) only: vmcnt=0, expcnt=7, lgkmcnt=15 -> 0x0F70
__device__ __forceinline__ void wait_vm0() { __builtin_amdgcn_s_waitcnt(0x0F70); }

__device__ __forceinline__ float fast_sig(float v) {
  return __builtin_amdgcn_rcpf(1.f + __expf(-v));
}

// XCD-aware decode: all NC col-blocks of a row-block share lin%8 -> same XCD.
template <int NC>
__device__ __forceinline__ void xcd_decode(int lin, int NR, int& r, int& c) {
  if (NR & 7) {  // fallback
    c = lin % NC;
    r = lin / NC;
  } else {
    int rl = lin & 7;
    int t = lin >> 3;
    c = t % NC;
    r = (t / NC) * 8 + rl;
  }
}

// ---------- probe: detect fp32 vs bf16 inputs (writes flag: 1 = fp32) ----------
__global__ void probe_kernel(const unsigned short* __restrict__ w0, int* __restrict__ flag) {
  __shared__ int s;
  if (threadIdx.x == 0) s = 0;
  __syncthreads();
  int big = 0;
  for (int i = threadIdx.x; i < 2048; i += 256) {
    unsigned e = (w0[i] >> 7) & 0xFFu;
    if (e >= 134u) big = 1;  // |val| >= 128 impossible for bf16 N(0,0.7) weights
  }
  if (big) atomicOr(&s, 1);
  __syncthreads();
  if (threadIdx.x == 0) *flag = s;
}

// ---------- generic convert to fp16 (zero-pads nIn..nOut) ----------
__global__ void cvt_kernel(const void* __restrict__ in, _Float16* __restrict__ out, int nOut,
                           int nIn, const int* __restrict__ flag) {
  int i = blockIdx.x * 256 + threadIdx.x;
  if (i >= nOut) return;
  float v = 0.f;
  if (i < nIn) v = (*flag) ? ((const float*)in)[i] : bfu2f(((const unsigned short*)in)[i]);
  out[i] = (_Float16)v;
}

// ---------- transpose+convert: out[z][n][k] = in[z][k][n] (n<Nin else 0), K=1024 ----------
__global__ void tr_kernel(const void* __restrict__ in, _Float16* __restrict__ out, int Nin,
                          long inStride, long outStride, const int* __restrict__ flag) {
  __shared__ float tile[32][33];
  const int f = *flag;
  int k0 = blockIdx.x * 32, n0 = blockIdx.y * 32;
  long ib = (long)blockIdx.z * inStride;
  long ob = (long)blockIdx.z * outStride;
  int tx = threadIdx.x, ty = threadIdx.y;  // 32 x 8
#pragma unroll
  for (int i = 0; i < 4; i++) {
    int k = k0 + ty + i * 8, n = n0 + tx;
    float v = 0.f;
    if (n < Nin) {
      long idx = ib + (long)k * Nin + n;
      v = f ? ((const float*)in)[idx] : bfu2f(((const unsigned short*)in)[idx]);
    }
    tile[ty + i * 8][tx] = v;
  }
  __syncthreads();
#pragma unroll
  for (int i = 0; i < 4; i++) {
    int n = n0 + ty + i * 8, k = k0 + tx;
    out[ob + (long)n * 1024 + k] = (_Float16)tile[tx][ty + i * 8];
  }
}

// ---------- layer 0: primal + 4 tangent init ----------
__global__ __launch_bounds__(256)
void layer0_kernel(const _Float16* __restrict__ x16, const _Float16* __restrict__ W0c,
                   const _Float16* __restrict__ b0c, _Float16* __restrict__ H,
                   int chunkBase, int S1) {
  const int lb = blockIdx.x;
  const int t = threadIdx.x;
  const long gb = (long)chunkBase + lb;
  float z0 = (float)x16[gb * 4 + 0];
  float z1 = (float)x16[gb * 4 + 1];
  float z2 = (float)x16[gb * 4 + 2];
  float z3 = (float)x16[gb * 4 + 3];
  const int j0 = t * 4;
  float w[4][4];
#pragma unroll
  for (int i = 0; i < 4; i++) {
    half4 wv = *(const half4*)&W0c[i * 1024 + j0];
#pragma unroll
    for (int jj = 0; jj < 4; jj++) w[i][jj] = (float)wv[jj];
  }
  half4 o[5];
#pragma unroll
  for (int jj = 0; jj < 4; jj++) {
    float pre = z0 * w[0][jj] + z1 * w[1][jj] + z2 * w[2][jj] + z3 * w[3][jj] +
                (float)b0c[j0 + jj];
    float s = fast_sig(pre);
    o[0][jj] = (_Float16)(pre * s);
    float ds = s * (1.f + pre * (1.f - s));
    o[1][jj] = (_Float16)(ds * w[0][jj]);
    o[2][jj] = (_Float16)(ds * w[1][jj]);
    o[3][jj] = (_Float16)(ds * w[2][jj]);
    o[4][jj] = (_Float16)(ds * w[3][jj]);
  }
  long rowbase = (long)lb * 1024 + j0;
#pragma unroll
  for (int s = 0; s < 5; s++) *(half4*)&H[(long)s * S1 + rowbase] = o[s];
}

// ---------- hidden primal GEMM: v = A*W^T + b; C = silu(v); DS = silu'(v) ----------
// Wave-autonomous K-loop: per-wave private LDS panels, no barriers inside.
__global__ __launch_bounds__(256, 4)
void gemm_h1(const _Float16* __restrict__ A, const _Float16* __restrict__ Bt,
             const _Float16* __restrict__ bias, _Float16* __restrict__ C,
             _Float16* __restrict__ DS, int NR) {
  constexpr int K = 1024;
  __shared__ _Float16 SM[16384];  // 4 waves x (A 2048 + B 2048); Ep(8192) overlays
  _Float16* Ep = SM;
  const int tid = threadIdx.x;
  const int wave = tid >> 6;
  const int lane = tid & 63;
  int rb, cb;
  xcd_decode<8>(blockIdx.x, NR, rb, cb);
  const int n0 = cb * 128;
  const long m0 = (long)rb * 128;

  const int wm = (wave & 1) * 64;
  const int wn = (wave >> 1) * 64;
  const int fr = lane & 15;
  const int fc = (lane >> 4) * 8;
  const int c0f = lane & 15;
  const int rqk = lane >> 4;
  const int myRound = wave & 1;

  _Float16* Apriv = SM + wave * 4096;
  _Float16* Bpriv = Apriv + 2048;
  const int srow = lane >> 2;
  const int scol = (lane & 3) * 8;
  const _Float16* gA = A + (m0 + wm + srow) * K + scol;
  const _Float16* gB = Bt + (long)(n0 + wn + srow) * K + scol;

  float bv[4];
#pragma unroll
  for (int ni = 0; ni < 4; ni++) bv[ni] = (float)bias[n0 + wn + ni * 16 + c0f];

  const int erow = tid >> 4;
  const int ecol = (tid & 15) * 8;
  const int ecolp = ecol ^ (wave << 4);

  floatx4 acc[4][4];
#pragma unroll
  for (int i = 0; i < 4; i++)
#pragma unroll
    for (int j = 0; j < 4; j++) acc[i][j] = (floatx4)(0.f);

  for (int kk = 0; kk < K; kk += 32) {
#pragma unroll
    for (int q = 0; q < 4; q++) gld16(gA + q * 16 * K + kk, Apriv + q * 512);
#pragma unroll
    for (int q = 0; q < 4; q++) gld16(gB + q * 16 * K + kk, Bpriv + q * 512);
    wait_vm0();
    half8 af[4], bf[4];
#pragma unroll
    for (int i = 0; i < 4; i++) af[i] = *(const half8*)&Apriv[(i * 16 + fr) * 32 + fc];
#pragma unroll
    for (int i = 0; i < 4; i++) bf[i] = *(const half8*)&Bpriv[(i * 16 + fr) * 32 + fc];
#pragma unroll
    for (int mi = 0; mi < 4; mi++)
#pragma unroll
      for (int ni = 0; ni < 4; ni++)
        acc[mi][ni] = __builtin_amdgcn_mfma_f32_16x16x32_f16(af[mi], bf[ni], acc[mi][ni], 0, 0, 0);
  }

#pragma unroll
  for (int r = 0; r < 2; r++) {
    __syncthreads();
    if (myRound == r) {
#pragma unroll
      for (int mi = 0; mi < 4; mi++)
#pragma unroll
        for (int ni = 0; ni < 4; ni++) {
          int colp = (wn + ni * 16 + c0f) ^ (rqk << 4);
#pragma unroll
          for (int rr = 0; rr < 4; rr++) {
            int row_local = mi * 16 + rqk * 4 + rr;
            Ep[row_local * 128 + colp] = (_Float16)(acc[mi][ni][rr] + bv[ni]);
          }
        }
    }
    __syncthreads();
#pragma unroll
    for (int p = 0; p < 4; p++) {
      int row_local = p * 16 + erow;
      half8 vv = *(const half8*)&Ep[row_local * 128 + ecolp];
      long row = m0 + r * 64 + row_local;
      half8 hv, dv;
#pragma unroll
      for (int e = 0; e < 8; e++) {
        float xv = (float)vv[e];
        float sg = fast_sig(xv);
        hv[e] = (_Float16)(xv * sg);
        dv[e] = (_Float16)(sg * (1.f + xv * (1.f - sg)));
      }
      *(half8*)&C[row * (long)K + n0 + ecol] = hv;
      *(half8*)&DS[row * (long)K + n0 + ecol] = dv;
    }
  }
}

// ---------- hidden tangent GEMM (4 streams in M): C = DS[row&mask] .* (A*W^T) ----------
__global__ __launch_bounds__(256, 4)
void gemm_h2(const _Float16* __restrict__ A, const _Float16* __restrict__ Bt,
             _Float16* __restrict__ C, const _Float16* __restrict__ DS, int bcMask, int NR) {
  constexpr int K = 1024;
  __shared__ _Float16 SM[16384];
  _Float16* Ep = SM;
  const int tid = threadIdx.x;
  const int wave = tid >> 6;
  const int lane = tid & 63;
  int rb, cb;
  xcd_decode<8>(blockIdx.x, NR, rb, cb);
  const int n0 = cb * 128;
  const long m0 = (long)rb * 128;

  const int wm = (wave & 1) * 64;
  const int wn = (wave >> 1) * 64;
  const int fr = lane & 15;
  const int fc = (lane >> 4) * 8;
  const int c0f = lane & 15;
  const int rqk = lane >> 4;
  const int myRound = wave & 1;

  _Float16* Apriv = SM + wave * 4096;
  _Float16* Bpriv = Apriv + 2048;
  const int srow = lane >> 2;
  const int scol = (lane & 3) * 8;
  const _Float16* gA = A + (m0 + wm + srow) * K + scol;
  const _Float16* gB = Bt + (long)(n0 + wn + srow) * K + scol;

  const int erow = tid >> 4;
  const int ecol = (tid & 15) * 8;
  const int ecolp = ecol ^ (wave << 4);

  floatx4 acc[4][4];
#pragma unroll
  for (int i = 0; i < 4; i++)
#pragma unroll
    for (int j = 0; j < 4; j++) acc[i][j] = (floatx4)(0.f);

  for (int kk = 0; kk < K; kk += 32) {
#pragma unroll
    for (int q = 0; q < 4; q++) gld16(gA + q * 16 * K + kk, Apriv + q * 512);
#pragma unroll
    for (int q = 0; q < 4; q++) gld16(gB + q * 16 * K + kk, Bpriv + q * 512);
    wait_vm0();
    half8 af[4], bf[4];
#pragma unroll
    for (int i = 0; i < 4; i++) af[i] = *(const half8*)&Apriv[(i * 16 + fr) * 32 + fc];
#pragma unroll
    for (int i = 0; i < 4; i++) bf[i] = *(const half8*)&Bpriv[(i * 16 + fr) * 32 + fc];
#pragma unroll
    for (int mi = 0; mi < 4; mi++)
#pragma unroll
      for (int ni = 0; ni < 4; ni++)
        acc[mi][ni] = __builtin_amdgcn_mfma_f32_16x16x32_f16(af[mi], bf[ni], acc[mi][ni], 0, 0, 0);
  }

#pragma unroll
  for (int r = 0; r < 2; r++) {
    __syncthreads();
    if (myRound == r) {
#pragma unroll
      for (int mi = 0; mi < 4; mi++)
#pragma unroll
        for (int ni = 0; ni < 4; ni++) {
          int colp = (wn + ni * 16 + c0f) ^ (rqk << 4);
#pragma unroll
          for (int rr = 0; rr < 4; rr++) {
            int row_local = mi * 16 + rqk * 4 + rr;
            Ep[row_local * 128 + colp] = (_Float16)acc[mi][ni][rr];
          }
        }
    }
    __syncthreads();
#pragma unroll
    for (int p = 0; p < 4; p++) {
      int row_local = p * 16 + erow;
      half8 vv = *(const half8*)&Ep[row_local * 128 + ecolp];
      long row = m0 + r * 64 + row_local;
      half8 dv = *(const half8*)&DS[(long)(row & bcMask) * K + n0 + ecol];
      *(half8*)&C[row * (long)K + n0 + ecol] = dv * vv;
    }
  }
}

// ---------- output GEMM: C(M x 448, ldc=448) = A*Bt^T (+bias rows < biasRows) ----------
__global__ __launch_bounds__(256, 4)
void gemm_out(const _Float16* __restrict__ A, const _Float16* __restrict__ Bt,
              const _Float16* __restrict__ bias, _Float16* __restrict__ C,
              int Nreal, int ldc, int biasRows, int NR) {
  constexpr int K = 1024;
  __shared__ _Float16 SM[16384];
  _Float16* Ep = SM;
  const int tid = threadIdx.x;
  const int wave = tid >> 6;
  const int lane = tid & 63;
  int rb, cb;
  xcd_decode<4>(blockIdx.x, NR, rb, cb);
  const int n0 = cb * 128;
  const long m0 = (long)rb * 128;

  const int wm = (wave & 1) * 64;
  const int wn = (wave >> 1) * 64;
  const int fr = lane & 15;
  const int fc = (lane >> 4) * 8;
  const int c0f = lane & 15;
  const int rqk = lane >> 4;
  const int myRound = wave & 1;

  _Float16* Apriv = SM + wave * 4096;
  _Float16* Bpriv = Apriv + 2048;
  const int srow = lane >> 2;
  const int scol = (lane & 3) * 8;
  const _Float16* gA = A + (m0 + wm + srow) * K + scol;
  const _Float16* gB = Bt + (long)(n0 + wn + srow) * K + scol;

  float bv[4];
#pragma unroll
  for (int ni = 0; ni < 4; ni++) bv[ni] = (float)bias[n0 + wn + ni * 16 + c0f];

  const int erow = tid >> 4;
  const int ecol = (tid & 15) * 8;
  const int ecolp = ecol ^ (wave << 4);

  floatx4 acc[4][4];
#pragma unroll
  for (int i = 0; i < 4; i++)
#pragma unroll
    for (int j = 0; j < 4; j++) acc[i][j] = (floatx4)(0.f);

  for (int kk = 0; kk < K; kk += 32) {
#pragma unroll
    for (int q = 0; q < 4; q++) gld16(gA + q * 16 * K + kk, Apriv + q * 512);
#pragma unroll
    for (int q = 0; q < 4; q++) gld16(gB + q * 16 * K + kk, Bpriv + q * 512);
    wait_vm0();
    half8 af[4], bf[4];
#pragma unroll
    for (int i = 0; i < 4; i++) af[i] = *(const half8*)&Apriv[(i * 16 + fr) * 32 + fc];
#pragma unroll
    for (int i = 0; i < 4; i++) bf[i] = *(const half8*)&Bpriv[(i * 16 + fr) * 32 + fc];
#pragma unroll
    for (int mi = 0; mi < 4; mi++)
#pragma unroll
      for (int ni = 0; ni < 4; ni++)
        acc[mi][ni] = __builtin_amdgcn_mfma_f32_16x16x32_f16(af[mi], bf[ni], acc[mi][ni], 0, 0, 0);
  }

#pragma unroll
  for (int r = 0; r < 2; r++) {
    __syncthreads();
    if (myRound == r) {
#pragma unroll
      for (int mi = 0; mi < 4; mi++)
#pragma unroll
        for (int ni = 0; ni < 4; ni++) {
          int colp = (wn + ni * 16 + c0f) ^ (rqk << 4);
#pragma unroll
          for (int rr = 0; rr < 4; rr++) {
            int row_local = mi * 16 + rqk * 4 + rr;
            long grow = m0 + wm + mi * 16 + rqk * 4 + rr;
            float v = acc[mi][ni][rr] + (grow < biasRows ? bv[ni] : 0.f);
            Ep[row_local * 128 + colp] = (_Float16)v;
          }
        }
    }
    __syncthreads();
#pragma unroll
    for (int p = 0; p < 4; p++) {
      int row_local = p * 16 + erow;
      int col = n0 + ecol;
      if (col < Nreal) {
        half8 vv = *(const half8*)&Ep[row_local * 128 + ecolp];
        long row = m0 + r * 64 + row_local;
        *(half8*)&C[row * (long)ldc + col] = vv;
      }
    }
  }
}

// ---------- finalize: softmax mixture + antisymmetric divergence; 1 wave = 1 sample ----------
__global__ __launch_bounds__(256)
void finalize_kernel(const _Float16* __restrict__ O5, void* __restrict__ outp,
                     int chunkBase, int Bc, const int* __restrict__ flag) {
  const int wid = threadIdx.x >> 6;
  const int lane = threadIdx.x & 63;  // lane == mixture index (N_MIX == 64)
  const int lb = blockIdx.x * 4 + wid;
  const long SO = (long)Bc * 448;
  const long base0 = (long)lb * 448;

  union UU { unsigned u; _Float16 h[2]; };

  float lg = (float)O5[base0 + lane];
  float vals[6];
  {
    const unsigned* vp = (const unsigned*)(O5 + base0 + 64 + lane * 6);
#pragma unroll
    for (int q = 0; q < 3; q++) {
      UU c; c.u = vp[q];
      vals[2 * q] = (float)c.h[0];
      vals[2 * q + 1] = (float)c.h[1];
    }
  }
  float dl[4], dv[4][6];
#pragma unroll
  for (int t = 0; t < 4; t++) {
    long bs = (long)(1 + t) * SO + base0;
    dl[t] = (float)O5[bs + lane];
    const unsigned* vp = (const unsigned*)(O5 + bs + 64 + lane * 6);
#pragma unroll
    for (int q = 0; q < 3; q++) {
      UU c; c.u = vp[q];
      dv[t][2 * q] = (float)c.h[0];
      dv[t][2 * q + 1] = (float)c.h[1];
    }
  }
  float mx = lg;
#pragma unroll
  for (int off = 32; off >= 1; off >>= 1) mx = fmaxf(mx, __shfl_xor(mx, off));
  float e = __expf(lg - mx);
  float S = e;
#pragma unroll
  for (int off = 32; off >= 1; off >>= 1) S += __shfl_xor(S, off);
  float pv = e / S;
  float st[4];
#pragma unroll
  for (int t = 0; t < 4; t++) {
    float v = pv * dl[t];
#pragma unroll
    for (int off = 32; off >= 1; off >>= 1) v += __shfl_xor(v, off);
    st[t] = v;
  }
  float da[4][6];
#pragma unroll
  for (int t = 0; t < 4; t++) {
    float w = pv * (dl[t] - st[t]);
#pragma unroll
    for (int k = 0; k < 6; k++) {
      float v = w * vals[k] + pv * dv[t][k];
#pragma unroll
      for (int off = 32; off >= 1; off >>= 1) v += __shfl_xor(v, off);
      da[t][k] = v;
    }
  }
  if (lane == 0) {
    float u0 = da[1][0] + da[2][1] + da[3][2];
    float u1 = -da[0][0] + da[2][3] + da[3][4];
    float u2 = -da[0][1] - da[1][3] + da[3][5];
    float u3 = -da[0][2] - da[1][4] - da[2][5];
    long ob = (long)(chunkBase + lb) * 4;
    if (*flag) {
      float* o = (float*)outp;
      o[ob] = 10.f * u0; o[ob + 1] = u1; o[ob + 2] = u2; o[ob + 3] = u3;
    } else {
      __hip_bfloat16* o = (__hip_bfloat16*)outp;
      o[ob] = __float2bfloat16(10.f * u0);
      o[ob + 1] = __float2bfloat16(u1);
      o[ob + 2] = __float2bfloat16(u2);
      o[ob + 3] = __float2bfloat16(u3);
    }
  }
}

extern "C" void kernel_launch(void* const* d_in, const int* in_sizes, int n_in,
                              void* d_out, int out_size, void* d_ws, size_t ws_size,
                              hipStream_t stream) {
  const void* x = d_in[0];
  const void* W0 = d_in[1];
  const void* b0 = d_in[2];
  const void* Wh = d_in[3];
  const void* bh = d_in[4];
  const void* Wout = d_in[5];
  const void* bout = d_in[6];
  const int B = in_sizes[0] / 4;  // 65536

  // workspace carve (all 256B-aligned)
  char* p = (char*)d_ws;
  int* flag = (int*)p;                 p += 256;
  _Float16* W0c = (_Float16*)p;        p += 4096 * 2;
  _Float16* b0c = (_Float16*)p;        p += 1024 * 2;
  _Float16* bhc = (_Float16*)p;        p += 4096 * 2;
  _Float16* boutc = (_Float16*)p;      p += 512 * 2;
  p += 256 - ((size_t)(p - (char*)d_ws) & 255);
  _Float16* x16 = (_Float16*)p;        p += (size_t)B * 4 * 2;
  _Float16* WhT = (_Float16*)p;        p += (size_t)4 * 1024 * 1024 * 2;
  _Float16* WoutT = (_Float16*)p;      p += (size_t)512 * 1024 * 2;  // padded 448->512 rows
  size_t used = (size_t)(p - (char*)d_ws);
  size_t rem = (ws_size > used) ? (ws_size - used) : 0;
  // per-sample: Ha(10240) + Hb(10240) + DS(2048) + PREo(4480)
  const size_t perS = 10240 + 10240 + 2048 + 4480;
  long bcap = (long)(rem / perS);
  int Bc = 128;
  while ((long)Bc * 2 <= bcap && Bc * 2 <= B) Bc *= 2;  // power of two, divides B
  _Float16* Ha = (_Float16*)p;         p += (size_t)5 * Bc * 1024 * 2;
  _Float16* Hb = (_Float16*)p;         p += (size_t)5 * Bc * 1024 * 2;
  _Float16* DS = (_Float16*)p;         p += (size_t)Bc * 1024 * 2;
  _Float16* PREo = (_Float16*)p;

  // dtype probe + weight prep (once per call)
  probe_kernel<<<1, 256, 0, stream>>>((const unsigned short*)W0, flag);
  cvt_kernel<<<(B * 4 + 255) / 256, 256, 0, stream>>>(x, x16, B * 4, B * 4, flag);
  cvt_kernel<<<16, 256, 0, stream>>>(W0, W0c, 4096, 4096, flag);
  cvt_kernel<<<4, 256, 0, stream>>>(b0, b0c, 1024, 1024, flag);
  cvt_kernel<<<16, 256, 0, stream>>>(bh, bhc, 4096, 4096, flag);
  cvt_kernel<<<2, 256, 0, stream>>>(bout, boutc, 512, 448, flag);
  tr_kernel<<<dim3(32, 32, 4), dim3(32, 8), 0, stream>>>(Wh, WhT, 1024, 1024L * 1024, 1024L * 1024, flag);
  tr_kernel<<<dim3(32, 16, 1), dim3(32, 8), 0, stream>>>(Wout, WoutT, 448, 0L, 0L, flag);

  const int nChunks = B / Bc;
  for (int c = 0; c < nChunks; c++) {
    const int base = c * Bc;
    const int S1 = Bc * 1024;
    _Float16* Hin = Ha;
    _Float16* Hout = Hb;
    layer0_kernel<<<Bc, 256, 0, stream>>>(x16, W0c, b0c, Hin, base, S1);
    const int NR1 = Bc / 128;
    const int NR2 = 4 * Bc / 128;
    const int NRo = 5 * Bc / 128;
    for (int l = 0; l < 4; l++) {
      const _Float16* Wl = WhT + (size_t)l * 1024 * 1024;
      gemm_h1<<<8 * NR1, 256, 0, stream>>>(
          Hin, Wl, bhc + l * 1024, Hout, DS, NR1);
      gemm_h2<<<8 * NR2, 256, 0, stream>>>(
          Hin + S1, Wl, Hout + S1, DS, Bc - 1, NR2);
      _Float16* t = Hin; Hin = Hout; Hout = t;
    }
    gemm_out<<<4 * NRo, 256, 0, stream>>>(
        Hin, WoutT, boutc, PREo, 448, 448, Bc, NRo);
    finalize_kernel<<<Bc / 4, 256, 0, stream>>>(PREo, d_out, base, Bc, flag);
  }
}

// Round 9
// 4498.519 us; speedup vs baseline: 1.2963x; 1.2963x over previous
//
#include <hip/hip_runtime.h>
#include <hip/hip_bf16.h>

typedef _Float16 half8 __attribute__((ext_vector_type(8)));
typedef _Float16 half4 __attribute__((ext_vector_type(4)));
typedef float floatx4 __attribute__((ext_vector_type(4)));

__device__ __forceinline__ float bfu2f(unsigned short u) {
  return __uint_as_float(((unsigned)u) << 16);
}

__device__ __forceinline__ void gld16(const void* g, void* l) {
  __builtin_amdgcn_global_load_lds((const __attribute__((address_space(1))) void*)g,
                                   (__attribute__((address_space(3))) void*)l, 16, 0, 0);
}

__device__ __forceinline__ float fast_sig(float v) {
  return __builtin_amdgcn_rcpf(1.f + __expf(-v));
}

// XCD-aware decode: all NC col-blocks of a row-block share lin%8 -> same XCD.
template <int NC>
__device__ __forceinline__ void xcd_decode(int lin, int NR, int& r, int& c) {
  if (NR & 7) {  // fallback
    c = lin % NC;
    r = lin / NC;
  } else {
    int rl = lin & 7;
    int t = lin >> 3;
    c = t % NC;
    r = (t / NC) * 8 + rl;
  }
}

// ---------- probe: detect fp32 vs bf16 inputs (writes flag: 1 = fp32) ----------
__global__ void probe_kernel(const unsigned short* __restrict__ w0, int* __restrict__ flag) {
  __shared__ int s;
  if (threadIdx.x == 0) s = 0;
  __syncthreads();
  int big = 0;
  for (int i = threadIdx.x; i < 2048; i += 256) {
    unsigned e = (w0[i] >> 7) & 0xFFu;
    if (e >= 134u) big = 1;  // |val| >= 128 impossible for bf16 N(0,0.7) weights
  }
  if (big) atomicOr(&s, 1);
  __syncthreads();
  if (threadIdx.x == 0) *flag = s;
}

// ---------- generic convert to fp16 (zero-pads nIn..nOut) ----------
__global__ void cvt_kernel(const void* __restrict__ in, _Float16* __restrict__ out, int nOut,
                           int nIn, const int* __restrict__ flag) {
  int i = blockIdx.x * 256 + threadIdx.x;
  if (i >= nOut) return;
  float v = 0.f;
  if (i < nIn) v = (*flag) ? ((const float*)in)[i] : bfu2f(((const unsigned short*)in)[i]);
  out[i] = (_Float16)v;
}

// ---------- transpose+convert: out[z][n][k] = in[z][k][n] (n<Nin else 0), K=1024 ----------
__global__ void tr_kernel(const void* __restrict__ in, _Float16* __restrict__ out, int Nin,
                          long inStride, long outStride, const int* __restrict__ flag) {
  __shared__ float tile[32][33];
  const int f = *flag;
  int k0 = blockIdx.x * 32, n0 = blockIdx.y * 32;
  long ib = (long)blockIdx.z * inStride;
  long ob = (long)blockIdx.z * outStride;
  int tx = threadIdx.x, ty = threadIdx.y;  // 32 x 8
#pragma unroll
  for (int i = 0; i < 4; i++) {
    int k = k0 + ty + i * 8, n = n0 + tx;
    float v = 0.f;
    if (n < Nin) {
      long idx = ib + (long)k * Nin + n;
      v = f ? ((const float*)in)[idx] : bfu2f(((const unsigned short*)in)[idx]);
    }
    tile[ty + i * 8][tx] = v;
  }
  __syncthreads();
#pragma unroll
  for (int i = 0; i < 4; i++) {
    int n = n0 + ty + i * 8, k = k0 + tx;
    out[ob + (long)n * 1024 + k] = (_Float16)tile[tx][ty + i * 8];
  }
}

// ---------- layer 0: primal + 4 tangent init ----------
__global__ __launch_bounds__(256)
void layer0_kernel(const _Float16* __restrict__ x16, const _Float16* __restrict__ W0c,
                   const _Float16* __restrict__ b0c, _Float16* __restrict__ H,
                   int chunkBase, int S1) {
  const int lb = blockIdx.x;
  const int t = threadIdx.x;
  const long gb = (long)chunkBase + lb;
  float z0 = (float)x16[gb * 4 + 0];
  float z1 = (float)x16[gb * 4 + 1];
  float z2 = (float)x16[gb * 4 + 2];
  float z3 = (float)x16[gb * 4 + 3];
  const int j0 = t * 4;
  float w[4][4];
#pragma unroll
  for (int i = 0; i < 4; i++) {
    half4 wv = *(const half4*)&W0c[i * 1024 + j0];
#pragma unroll
    for (int jj = 0; jj < 4; jj++) w[i][jj] = (float)wv[jj];
  }
  half4 o[5];
#pragma unroll
  for (int jj = 0; jj < 4; jj++) {
    float pre = z0 * w[0][jj] + z1 * w[1][jj] + z2 * w[2][jj] + z3 * w[3][jj] +
                (float)b0c[j0 + jj];
    float s = fast_sig(pre);
    o[0][jj] = (_Float16)(pre * s);
    float ds = s * (1.f + pre * (1.f - s));
    o[1][jj] = (_Float16)(ds * w[0][jj]);
    o[2][jj] = (_Float16)(ds * w[1][jj]);
    o[3][jj] = (_Float16)(ds * w[2][jj]);
    o[4][jj] = (_Float16)(ds * w[3][jj]);
  }
  long rowbase = (long)lb * 1024 + j0;
#pragma unroll
  for (int s = 0; s < 5; s++) *(half4*)&H[(long)s * S1 + rowbase] = o[s];
}

// ---------- hidden primal GEMM: v = A*W^T + b; C = silu(v); DS = silu'(v) ----------
__global__ __launch_bounds__(256, 3)
void gemm_h1(const _Float16* __restrict__ A, const _Float16* __restrict__ Bt,
             const _Float16* __restrict__ bias, _Float16* __restrict__ C,
             _Float16* __restrict__ DS, int NR) {
  constexpr int K = 1024;
  __shared__ _Float16 SM[8192];  // As(4096) + Bs(4096); Ep(8192) overlaps after K-loop
  _Float16* As = SM;
  _Float16* Bs = SM + 4096;
  _Float16* Ep = SM;
  const int tid = threadIdx.x;
  const int wave = tid >> 6;
  const int lane = tid & 63;
  int rb, cb;
  xcd_decode<8>(blockIdx.x, NR, rb, cb);
  const int n0 = cb * 128;
  const long m0 = (long)rb * 128;

  const int srow0 = (wave * 2 + 0) * 16 + (lane >> 2);
  const int srow1 = (wave * 2 + 1) * 16 + (lane >> 2);
  const int scol = (lane & 3) * 8;
  const _Float16* gA0 = A + (m0 + srow0) * K + scol;
  const _Float16* gA1 = A + (m0 + srow1) * K + scol;
  const _Float16* gB0 = Bt + (long)(n0 + srow0) * K + scol;
  const _Float16* gB1 = Bt + (long)(n0 + srow1) * K + scol;
  _Float16* lA0 = As + (wave * 2 + 0) * 512;
  _Float16* lA1 = As + (wave * 2 + 1) * 512;
  _Float16* lB0 = Bs + (wave * 2 + 0) * 512;
  _Float16* lB1 = Bs + (wave * 2 + 1) * 512;

  const int wm = (wave & 1) * 64;
  const int wn = (wave >> 1) * 64;
  const int fr = lane & 15;
  const int fc = (lane >> 4) * 8;
  const int c0f = lane & 15;
  const int rqk = lane >> 4;
  const int myRound = wave & 1;

  float bv[4];
#pragma unroll
  for (int ni = 0; ni < 4; ni++) bv[ni] = (float)bias[n0 + wn + ni * 16 + c0f];

  const int erow = tid >> 4;
  const int ecol = (tid & 15) * 8;
  const int ecolp = ecol ^ (wave << 4);

  floatx4 acc[4][4];
#pragma unroll
  for (int i = 0; i < 4; i++)
#pragma unroll
    for (int j = 0; j < 4; j++) acc[i][j] = (floatx4)(0.f);

  for (int kk = 0; kk < K; kk += 32) {
    __syncthreads();
    gld16(gA0 + kk, lA0);
    gld16(gA1 + kk, lA1);
    gld16(gB0 + kk, lB0);
    gld16(gB1 + kk, lB1);
    __syncthreads();
    half8 af[4], bf[4];
#pragma unroll
    for (int i = 0; i < 4; i++) af[i] = *(const half8*)&As[(wm + i * 16 + fr) * 32 + fc];
#pragma unroll
    for (int i = 0; i < 4; i++) bf[i] = *(const half8*)&Bs[(wn + i * 16 + fr) * 32 + fc];
#pragma unroll
    for (int mi = 0; mi < 4; mi++)
#pragma unroll
      for (int ni = 0; ni < 4; ni++)
        acc[mi][ni] = __builtin_amdgcn_mfma_f32_16x16x32_f16(af[mi], bf[ni], acc[mi][ni], 0, 0, 0);
  }

#pragma unroll
  for (int r = 0; r < 2; r++) {
    __syncthreads();
    if (myRound == r) {
#pragma unroll
      for (int mi = 0; mi < 4; mi++)
#pragma unroll
        for (int ni = 0; ni < 4; ni++) {
          int colp = (wn + ni * 16 + c0f) ^ (rqk << 4);
#pragma unroll
          for (int rr = 0; rr < 4; rr++) {
            int row_local = mi * 16 + rqk * 4 + rr;
            Ep[row_local * 128 + colp] = (_Float16)(acc[mi][ni][rr] + bv[ni]);
          }
        }
    }
    __syncthreads();
#pragma unroll
    for (int p = 0; p < 4; p++) {
      int row_local = p * 16 + erow;
      half8 vv = *(const half8*)&Ep[row_local * 128 + ecolp];
      long row = m0 + r * 64 + row_local;
      half8 hv, dv;
#pragma unroll
      for (int e = 0; e < 8; e++) {
        float xv = (float)vv[e];
        float sg = fast_sig(xv);
        hv[e] = (_Float16)(xv * sg);
        dv[e] = (_Float16)(sg * (1.f + xv * (1.f - sg)));
      }
      *(half8*)&C[row * (long)K + n0 + ecol] = hv;
      *(half8*)&DS[row * (long)K + n0 + ecol] = dv;
    }
  }
}

// ---------- hidden tangent GEMM (4 streams in M): C = DS[row&mask] .* (A*W^T) ----------
// Triple-buffered K-loop, prefetch distance 2, raw s_barrier + explicit vmcnt.
__global__ __launch_bounds__(256, 3)
void gemm_h2(const _Float16* __restrict__ A, const _Float16* __restrict__ Bt,
             _Float16* __restrict__ C, const _Float16* __restrict__ DS, int bcMask, int NR) {
  constexpr int K = 1024;
  __shared__ _Float16 SM[24576];  // 3 buffers x (A 4096 + B 4096) halves = 48 KB; Ep overlays buf0
  _Float16* Ep = SM;
  const int tid = threadIdx.x;
  const int wave = tid >> 6;
  const int lane = tid & 63;
  int rb, cb;
  xcd_decode<8>(blockIdx.x, NR, rb, cb);
  const int n0 = cb * 128;
  const long m0 = (long)rb * 128;

  const int srow0 = (wave * 2 + 0) * 16 + (lane >> 2);
  const int srow1 = (wave * 2 + 1) * 16 + (lane >> 2);
  const int scol = (lane & 3) * 8;
  const _Float16* gA0 = A + (m0 + srow0) * K + scol;
  const _Float16* gA1 = A + (m0 + srow1) * K + scol;
  const _Float16* gB0 = Bt + (long)(n0 + srow0) * K + scol;
  const _Float16* gB1 = Bt + (long)(n0 + srow1) * K + scol;
  const int loffA0 = (wave * 2 + 0) * 512;
  const int loffA1 = (wave * 2 + 1) * 512;

  const int wm = (wave & 1) * 64;
  const int wn = (wave >> 1) * 64;
  const int fr = lane & 15;
  const int fc = (lane >> 4) * 8;
  const int c0f = lane & 15;
  const int rqk = lane >> 4;
  const int myRound = wave & 1;

  const int erow = tid >> 4;
  const int ecol = (tid & 15) * 8;
  const int ecolp = ecol ^ (wave << 4);

  floatx4 acc[4][4];
#pragma unroll
  for (int i = 0; i < 4; i++)
#pragma unroll
    for (int j = 0; j < 4; j++) acc[i][j] = (floatx4)(0.f);

  // prologue: stage tiles 0 and 1
  {
    _Float16* b0p = SM;
    gld16(gA0 + 0, b0p + loffA0);
    gld16(gA1 + 0, b0p + loffA1);
    gld16(gB0 + 0, b0p + 4096 + loffA0);
    gld16(gB1 + 0, b0p + 4096 + loffA1);
    _Float16* b1p = SM + 8192;
    gld16(gA0 + 32, b1p + loffA0);
    gld16(gA1 + 32, b1p + loffA1);
    gld16(gB0 + 32, b1p + 4096 + loffA0);
    gld16(gB1 + 32, b1p + 4096 + loffA1);
  }

  int bufCur = 0;   // buffer holding tile `it`
  int bufNxt = 2;   // buffer to receive tile `it+2`
  for (int it = 0; it < 32; ++it) {
    // wait for tile `it` (4 newest loads = tile it+1 may remain in flight)
    if (it < 31) __builtin_amdgcn_s_waitcnt(0x0F74);  // vmcnt(4)
    else         __builtin_amdgcn_s_waitcnt(0x0F70);  // vmcnt(0)
    __builtin_amdgcn_s_barrier();                     // raw barrier: no forced drain of tile it+1
    if (it < 30) {
      const int kk = (it + 2) * 32;
      _Float16* bp = SM + bufNxt * 8192;
      gld16(gA0 + kk, bp + loffA0);
      gld16(gA1 + kk, bp + loffA1);
      gld16(gB0 + kk, bp + 4096 + loffA0);
      gld16(gB1 + kk, bp + 4096 + loffA1);
    }
    const _Float16* Asb = SM + bufCur * 8192;
    const _Float16* Bsb = Asb + 4096;
    half8 af[4], bf[4];
#pragma unroll
    for (int i = 0; i < 4; i++) af[i] = *(const half8*)&Asb[(wm + i * 16 + fr) * 32 + fc];
#pragma unroll
    for (int i = 0; i < 4; i++) bf[i] = *(const half8*)&Bsb[(wn + i * 16 + fr) * 32 + fc];
#pragma unroll
    for (int mi = 0; mi < 4; mi++)
#pragma unroll
      for (int ni = 0; ni < 4; ni++)
        acc[mi][ni] = __builtin_amdgcn_mfma_f32_16x16x32_f16(af[mi], bf[ni], acc[mi][ni], 0, 0, 0);
    bufCur = (bufCur == 2) ? 0 : bufCur + 1;
    bufNxt = (bufNxt == 2) ? 0 : bufNxt + 1;
  }

#pragma unroll
  for (int r = 0; r < 2; r++) {
    __syncthreads();
    if (myRound == r) {
#pragma unroll
      for (int mi = 0; mi < 4; mi++)
#pragma unroll
        for (int ni = 0; ni < 4; ni++) {
          int colp = (wn + ni * 16 + c0f) ^ (rqk << 4);
#pragma unroll
          for (int rr = 0; rr < 4; rr++) {
            int row_local = mi * 16 + rqk * 4 + rr;
            Ep[row_local * 128 + colp] = (_Float16)acc[mi][ni][rr];
          }
        }
    }
    __syncthreads();
#pragma unroll
    for (int p = 0; p < 4; p++) {
      int row_local = p * 16 + erow;
      half8 vv = *(const half8*)&Ep[row_local * 128 + ecolp];
      long row = m0 + r * 64 + row_local;
      half8 dv = *(const half8*)&DS[(long)(row & bcMask) * K + n0 + ecol];
      *(half8*)&C[row * (long)K + n0 + ecol] = dv * vv;
    }
  }
}

// ---------- output GEMM: C(M x 448, ldc=448) = A*Bt^T (+bias rows < biasRows) ----------
__global__ __launch_bounds__(256, 4)
void gemm_out(const _Float16* __restrict__ A, const _Float16* __restrict__ Bt,
              const _Float16* __restrict__ bias, _Float16* __restrict__ C,
              int Nreal, int ldc, int biasRows, int NR) {
  constexpr int K = 1024;
  __shared__ _Float16 SM[8192];
  _Float16* As = SM;
  _Float16* Bs = SM + 4096;
  _Float16* Ep = SM;
  const int tid = threadIdx.x;
  const int wave = tid >> 6;
  const int lane = tid & 63;
  int rb, cb;
  xcd_decode<4>(blockIdx.x, NR, rb, cb);
  const int n0 = cb * 128;
  const long m0 = (long)rb * 128;

  const int srow0 = (wave * 2 + 0) * 16 + (lane >> 2);
  const int srow1 = (wave * 2 + 1) * 16 + (lane >> 2);
  const int scol = (lane & 3) * 8;
  const _Float16* gA0 = A + (m0 + srow0) * K + scol;
  const _Float16* gA1 = A + (m0 + srow1) * K + scol;
  const _Float16* gB0 = Bt + (long)(n0 + srow0) * K + scol;
  const _Float16* gB1 = Bt + (long)(n0 + srow1) * K + scol;
  _Float16* lA0 = As + (wave * 2 + 0) * 512;
  _Float16* lA1 = As + (wave * 2 + 1) * 512;
  _Float16* lB0 = Bs + (wave * 2 + 0) * 512;
  _Float16* lB1 = Bs + (wave * 2 + 1) * 512;

  const int wm = (wave & 1) * 64;
  const int wn = (wave >> 1) * 64;
  const int fr = lane & 15;
  const int fc = (lane >> 4) * 8;
  const int c0f = lane & 15;
  const int rqk = lane >> 4;
  const int myRound = wave & 1;

  float bv[4];
#pragma unroll
  for (int ni = 0; ni < 4; ni++) bv[ni] = (float)bias[n0 + wn + ni * 16 + c0f];

  const int erow = tid >> 4;
  const int ecol = (tid & 15) * 8;
  const int ecolp = ecol ^ (wave << 4);

  floatx4 acc[4][4];
#pragma unroll
  for (int i = 0; i < 4; i++)
#pragma unroll
    for (int j = 0; j < 4; j++) acc[i][j] = (floatx4)(0.f);

  for (int kk = 0; kk < K; kk += 32) {
    __syncthreads();
    gld16(gA0 + kk, lA0);
    gld16(gA1 + kk, lA1);
    gld16(gB0 + kk, lB0);
    gld16(gB1 + kk, lB1);
    __syncthreads();
    half8 af[4], bf[4];
#pragma unroll
    for (int i = 0; i < 4; i++) af[i] = *(const half8*)&As[(wm + i * 16 + fr) * 32 + fc];
#pragma unroll
    for (int i = 0; i < 4; i++) bf[i] = *(const half8*)&Bs[(wn + i * 16 + fr) * 32 + fc];
#pragma unroll
    for (int mi = 0; mi < 4; mi++)
#pragma unroll
      for (int ni = 0; ni < 4; ni++)
        acc[mi][ni] = __builtin_amdgcn_mfma_f32_16x16x32_f16(af[mi], bf[ni], acc[mi][ni], 0, 0, 0);
  }

#pragma unroll
  for (int r = 0; r < 2; r++) {
    __syncthreads();
    if (myRound == r) {
#pragma unroll
      for (int mi = 0; mi < 4; mi++)
#pragma unroll
        for (int ni = 0; ni < 4; ni++) {
          int colp = (wn + ni * 16 + c0f) ^ (rqk << 4);
#pragma unroll
          for (int rr = 0; rr < 4; rr++) {
            int row_local = mi * 16 + rqk * 4 + rr;
            long grow = m0 + wm + mi * 16 + rqk * 4 + rr;
            float v = acc[mi][ni][rr] + (grow < biasRows ? bv[ni] : 0.f);
            Ep[row_local * 128 + colp] = (_Float16)v;
          }
        }
    }
    __syncthreads();
#pragma unroll
    for (int p = 0; p < 4; p++) {
      int row_local = p * 16 + erow;
      int col = n0 + ecol;
      if (col < Nreal) {
        half8 vv = *(const half8*)&Ep[row_local * 128 + ecolp];
        long row = m0 + r * 64 + row_local;
        *(half8*)&C[row * (long)ldc + col] = vv;
      }
    }
  }
}

// ---------- finalize: softmax mixture + antisymmetric divergence; 1 wave = 1 sample ----------
__global__ __launch_bounds__(256)
void finalize_kernel(const _Float16* __restrict__ O5, void* __restrict__ outp,
                     int chunkBase, int Bc, const int* __restrict__ flag) {
  const int wid = threadIdx.x >> 6;
  const int lane = threadIdx.x & 63;  // lane == mixture index (N_MIX == 64)
  const int lb = blockIdx.x * 4 + wid;
  const long SO = (long)Bc * 448;
  const long base0 = (long)lb * 448;

  union UU { unsigned u; _Float16 h[2]; };

  float lg = (float)O5[base0 + lane];
  float vals[6];
  {
    const unsigned* vp = (const unsigned*)(O5 + base0 + 64 + lane * 6);
#pragma unroll
    for (int q = 0; q < 3; q++) {
      UU c; c.u = vp[q];
      vals[2 * q] = (float)c.h[0];
      vals[2 * q + 1] = (float)c.h[1];
    }
  }
  float dl[4], dv[4][6];
#pragma unroll
  for (int t = 0; t < 4; t++) {
    long bs = (long)(1 + t) * SO + base0;
    dl[t] = (float)O5[bs + lane];
    const unsigned* vp = (const unsigned*)(O5 + bs + 64 + lane * 6);
#pragma unroll
    for (int q = 0; q < 3; q++) {
      UU c; c.u = vp[q];
      dv[t][2 * q] = (float)c.h[0];
      dv[t][2 * q + 1] = (float)c.h[1];
    }
  }
  float mx = lg;
#pragma unroll
  for (int off = 32; off >= 1; off >>= 1) mx = fmaxf(mx, __shfl_xor(mx, off));
  float e = __expf(lg - mx);
  float S = e;
#pragma unroll
  for (int off = 32; off >= 1; off >>= 1) S += __shfl_xor(S, off);
  float pv = e / S;
  float st[4];
#pragma unroll
  for (int t = 0; t < 4; t++) {
    float v = pv * dl[t];
#pragma unroll
    for (int off = 32; off >= 1; off >>= 1) v += __shfl_xor(v, off);
    st[t] = v;
  }
  float da[4][6];
#pragma unroll
  for (int t = 0; t < 4; t++) {
    float w = pv * (dl[t] - st[t]);
#pragma unroll
    for (int k = 0; k < 6; k++) {
      float v = w * vals[k] + pv * dv[t][k];
#pragma unroll
      for (int off = 32; off >= 1; off >>= 1) v += __shfl_xor(v, off);
      da[t][k] = v;
    }
  }
  if (lane == 0) {
    float u0 = da[1][0] + da[2][1] + da[3][2];
    float u1 = -da[0][0] + da[2][3] + da[3][4];
    float u2 = -da[0][1] - da[1][3] + da[3][5];
    float u3 = -da[0][2] - da[1][4] - da[2][5];
    long ob = (long)(chunkBase + lb) * 4;
    if (*flag) {
      float* o = (float*)outp;
      o[ob] = 10.f * u0; o[ob + 1] = u1; o[ob + 2] = u2; o[ob + 3] = u3;
    } else {
      __hip_bfloat16* o = (__hip_bfloat16*)outp;
      o[ob] = __float2bfloat16(10.f * u0);
      o[ob + 1] = __float2bfloat16(u1);
      o[ob + 2] = __float2bfloat16(u2);
      o[ob + 3] = __float2bfloat16(u3);
    }
  }
}

extern "C" void kernel_launch(void* const* d_in, const int* in_sizes, int n_in,
                              void* d_out, int out_size, void* d_ws, size_t ws_size,
                              hipStream_t stream) {
  const void* x = d_in[0];
  const void* W0 = d_in[1];
  const void* b0 = d_in[2];
  const void* Wh = d_in[3];
  const void* bh = d_in[4];
  const void* Wout = d_in[5];
  const void* bout = d_in[6];
  const int B = in_sizes[0] / 4;  // 65536

  // workspace carve (all 256B-aligned)
  char* p = (char*)d_ws;
  int* flag = (int*)p;                 p += 256;
  _Float16* W0c = (_Float16*)p;        p += 4096 * 2;
  _Float16* b0c = (_Float16*)p;        p += 1024 * 2;
  _Float16* bhc = (_Float16*)p;        p += 4096 * 2;
  _Float16* boutc = (_Float16*)p;      p += 512 * 2;
  p += 256 - ((size_t)(p - (char*)d_ws) & 255);
  _Float16* x16 = (_Float16*)p;        p += (size_t)B * 4 * 2;
  _Float16* WhT = (_Float16*)p;        p += (size_t)4 * 1024 * 1024 * 2;
  _Float16* WoutT = (_Float16*)p;      p += (size_t)512 * 1024 * 2;  // padded 448->512 rows
  size_t used = (size_t)(p - (char*)d_ws);
  size_t rem = (ws_size > used) ? (ws_size - used) : 0;
  // per-sample: Ha(10240) + Hb(10240) + DS(2048) + PREo(4480)
  const size_t perS = 10240 + 10240 + 2048 + 4480;
  long bcap = (long)(rem / perS);
  int Bc = 128;
  while ((long)Bc * 2 <= bcap && Bc * 2 <= B) Bc *= 2;  // power of two, divides B
  _Float16* Ha = (_Float16*)p;         p += (size_t)5 * Bc * 1024 * 2;
  _Float16* Hb = (_Float16*)p;         p += (size_t)5 * Bc * 1024 * 2;
  _Float16* DS = (_Float16*)p;         p += (size_t)Bc * 1024 * 2;
  _Float16* PREo = (_Float16*)p;

  // dtype probe + weight prep (once per call)
  probe_kernel<<<1, 256, 0, stream>>>((const unsigned short*)W0, flag);
  cvt_kernel<<<(B * 4 + 255) / 256, 256, 0, stream>>>(x, x16, B * 4, B * 4, flag);
  cvt_kernel<<<16, 256, 0, stream>>>(W0, W0c, 4096, 4096, flag);
  cvt_kernel<<<4, 256, 0, stream>>>(b0, b0c, 1024, 1024, flag);
  cvt_kernel<<<16, 256, 0, stream>>>(bh, bhc, 4096, 4096, flag);
  cvt_kernel<<<2, 256, 0, stream>>>(bout, boutc, 512, 448, flag);
  tr_kernel<<<dim3(32, 32, 4), dim3(32, 8), 0, stream>>>(Wh, WhT, 1024, 1024L * 1024, 1024L * 1024, flag);
  tr_kernel<<<dim3(32, 16, 1), dim3(32, 8), 0, stream>>>(Wout, WoutT, 448, 0L, 0L, flag);

  const int nChunks = B / Bc;
  for (int c = 0; c < nChunks; c++) {
    const int base = c * Bc;
    const int S1 = Bc * 1024;
    _Float16* Hin = Ha;
    _Float16* Hout = Hb;
    layer0_kernel<<<Bc, 256, 0, stream>>>(x16, W0c, b0c, Hin, base, S1);
    const int NR1 = Bc / 128;
    const int NR2 = 4 * Bc / 128;
    const int NRo = 5 * Bc / 128;
    for (int l = 0; l < 4; l++) {
      const _Float16* Wl = WhT + (size_t)l * 1024 * 1024;
      gemm_h1<<<8 * NR1, 256, 0, stream>>>(
          Hin, Wl, bhc + l * 1024, Hout, DS, NR1);
      gemm_h2<<<8 * NR2, 256, 0, stream>>>(
          Hin + S1, Wl, Hout + S1, DS, Bc - 1, NR2);
      _Float16* t = Hin; Hin = Hout; Hout = t;
    }
    gemm_out<<<4 * NRo, 256, 0, stream>>>(
        Hin, WoutT, boutc, PREo, 448, 448, Bc, NRo);
    finalize_kernel<<<Bc / 4, 256, 0, stream>>>(PREo, d_out, base, Bc, flag);
  }
}